// Round 1
// baseline (1156.896 us; speedup 1.0000x reference)
//
#include <hip/hip_runtime.h>
#include <stdint.h>

#define BB 2
#define LL 2048
#define DD 1024
#define HH 16
#define DKK 64

typedef __attribute__((ext_vector_type(8))) short short8;
typedef __attribute__((ext_vector_type(4))) float f32x4;

__device__ __forceinline__ unsigned short f2bf(float x) {
    union { float f; unsigned int u; } v; v.f = x;
    unsigned int r = v.u + 0x7FFFu + ((v.u >> 16) & 1u);
    return (unsigned short)(r >> 16);
}

// ---------------- W fp32 -> bf16 ----------------
__global__ __launch_bounds__(256) void k_convw(
        const float* __restrict__ w0, const float* __restrict__ w1,
        const float* __restrict__ w2, const float* __restrict__ w3,
        unsigned short* __restrict__ dst) {
    int which = blockIdx.y;
    const float* s = which==0?w0: which==1?w1: which==2?w2: w3;
    unsigned short* d = dst + (size_t)which * (DD*DD);
    int i = (blockIdx.x * 256 + threadIdx.x) * 4;
    float4 f = *(const float4*)(s + i);
    ushort4 o;
    o.x = f2bf(f.x); o.y = f2bf(f.y); o.z = f2bf(f.z); o.w = f2bf(f.w);
    *(ushort4*)(d + i) = o;
}

// ---------------- mask (B,L,L) int32 -> bitmask ----------------
__global__ __launch_bounds__(256) void k_mask(
        const int* __restrict__ mask, unsigned long long* __restrict__ bits) {
    int tid = blockIdx.x * 256 + threadIdx.x;
    unsigned long long w = __ballot(mask[tid] != 0);
    if ((threadIdx.x & 63) == 0) bits[tid >> 6] = w;
}

// ---------------- LayerNorm -> bf16 (q,k,v via blockIdx.y) ----------------
__global__ __launch_bounds__(256) void k_ln(
        const float* __restrict__ q, const float* __restrict__ k, const float* __restrict__ v,
        const float* __restrict__ gq, const float* __restrict__ bq,
        const float* __restrict__ gk, const float* __restrict__ bk,
        const float* __restrict__ gv, const float* __restrict__ bv,
        unsigned short* __restrict__ xn) {
    int which = blockIdx.y;
    const float* x = which==0?q: which==1?k: v;
    const float* g = which==0?gq: which==1?gk: gv;
    const float* be = which==0?bq: which==1?bk: bv;
    unsigned short* o = xn + (size_t)which * ((size_t)BB*LL*DD);
    int row = blockIdx.x;
    int t = threadIdx.x;
    const float* xr = x + (size_t)row * DD;
    float4 xv = *(const float4*)(xr + t*4);
    float s  = xv.x + xv.y + xv.z + xv.w;
    float s2 = xv.x*xv.x + xv.y*xv.y + xv.z*xv.z + xv.w*xv.w;
    #pragma unroll
    for (int off = 32; off > 0; off >>= 1) {
        s  += __shfl_down(s, off);
        s2 += __shfl_down(s2, off);
    }
    __shared__ float red[8];
    if ((t & 63) == 0) { red[t>>6] = s; red[4 + (t>>6)] = s2; }
    __syncthreads();
    s  = red[0]+red[1]+red[2]+red[3];
    s2 = red[4]+red[5]+red[6]+red[7];
    float mu  = s * (1.0f/DD);
    float var = s2 * (1.0f/DD) - mu*mu;
    float rs  = rsqrtf(var + 1e-5f);
    float4 gg = *(const float4*)(g + t*4);
    float4 bb = *(const float4*)(be + t*4);
    ushort4 ov;
    ov.x = f2bf((xv.x-mu)*rs*gg.x + bb.x);
    ov.y = f2bf((xv.y-mu)*rs*gg.y + bb.y);
    ov.z = f2bf((xv.z-mu)*rs*gg.z + bb.z);
    ov.w = f2bf((xv.w-mu)*rs*gg.w + bb.w);
    *(ushort4*)(o + (size_t)row*DD + t*4) = ov;
}

// ---------------- GEMM: C[m][n] = sum_k A[m][k]*W[n][k]  (M=4096,N=1024,K=1024)
// mode 0: bf16 out [b,h,l,dk]   mode 1: bf16 out [b,h,dk,l]   mode 2: fp32 out + resid
__global__ __launch_bounds__(256) void k_gemm(
        const unsigned short* __restrict__ A, const unsigned short* __restrict__ W,
        void* __restrict__ Cout, const float* __restrict__ resid, int mode) {
    __shared__ unsigned short As[64][40];
    __shared__ unsigned short Bs[64][40];
    int m0 = blockIdx.x * 64;
    int n0 = blockIdx.y * 64;
    int t = threadIdx.x;
    int lane = t & 63, wv = t >> 6;
    int quad = lane >> 4, l16 = lane & 15;
    f32x4 acc[4];
    #pragma unroll
    for (int i = 0; i < 4; ++i) acc[i] = (f32x4){0.f,0.f,0.f,0.f};
    int srow = t >> 2;
    int scol = (t & 3) * 8;
    for (int kc = 0; kc < 32; ++kc) {
        int k0 = kc * 32;
        *(short8*)(&As[srow][scol]) = *(const short8*)(A + (size_t)(m0+srow)*DD + k0 + scol);
        *(short8*)(&Bs[srow][scol]) = *(const short8*)(W + (size_t)(n0+srow)*DD + k0 + scol);
        __syncthreads();
        short8 af = *(const short8*)(&As[wv*16 + l16][quad*8]);
        #pragma unroll
        for (int nt = 0; nt < 4; ++nt) {
            short8 bf = *(const short8*)(&Bs[nt*16 + l16][quad*8]);
            acc[nt] = __builtin_amdgcn_mfma_f32_16x16x32_bf16(af, bf, acc[nt], 0, 0, 0);
        }
        __syncthreads();
    }
    #pragma unroll
    for (int nt = 0; nt < 4; ++nt) {
        #pragma unroll
        for (int r = 0; r < 4; ++r) {
            int m = m0 + wv*16 + quad*4 + r;
            int n = n0 + nt*16 + l16;
            float val = acc[nt][r];
            if (mode == 2) {
                ((float*)Cout)[(size_t)m*DD + n] = val + resid[(size_t)m*DD + n];
            } else {
                int b = m >> 11, l = m & 2047, h = n >> 6, dk = n & 63;
                if (mode == 0)
                    ((unsigned short*)Cout)[((size_t)(b*HH+h)*LL + l)*DKK + dk] = f2bf(val);
                else
                    ((unsigned short*)Cout)[((size_t)(b*HH+h)*DKK + dk)*LL + l] = f2bf(val);
            }
        }
    }
}

// ---------------- fused attention per (qtile, b*h) ----------------
// qh,kh: [b,h,l,dk] bf16 ; vT: [b,h,dk,l] bf16 ; attn -> fp32 ; AO -> bf16 [b*l][1024]
__global__ __launch_bounds__(256) void k_attn(
        const unsigned short* __restrict__ qh, const unsigned short* __restrict__ kh,
        const unsigned short* __restrict__ vT, const unsigned int* __restrict__ mbits,
        float* __restrict__ attn, unsigned short* __restrict__ AO) {
    int qt = blockIdx.x;   // 0..31
    int bh = blockIdx.y;   // 0..31
    int b = bh >> 4, h = bh & 15;
    int t = threadIdx.x, lane = t & 63, wv = t >> 6;
    int quad = lane >> 4, l16 = lane & 15;
    int q0 = qt*64 + wv*16;           // wave's 16 q-rows start
    const unsigned short* Qb = qh + (size_t)bh * LL * DKK;
    const unsigned short* Kb = kh + (size_t)bh * LL * DKK;
    const unsigned short* Vb = vT + (size_t)bh * DKK * LL;

    short8 qf0 = *(const short8*)(Qb + (size_t)(q0 + l16)*DKK + quad*8);
    short8 qf1 = *(const short8*)(Qb + (size_t)(q0 + l16)*DKK + 32 + quad*8);

    float mrow[4], lrow[4];
    #pragma unroll
    for (int r = 0; r < 4; ++r) { mrow[r] = -1e30f; lrow[r] = 0.f; }

    // ---- pass 1: online row max / sumexp ----
    for (int kt = 0; kt < 32; ++kt) {
        float s[4][4];
        #pragma unroll
        for (int nt = 0; nt < 4; ++nt) {
            const unsigned short* Kp = Kb + (size_t)(kt*64 + nt*16 + l16)*DKK;
            short8 kf0 = *(const short8*)(Kp + quad*8);
            short8 kf1 = *(const short8*)(Kp + 32 + quad*8);
            f32x4 c = (f32x4){0.f,0.f,0.f,0.f};
            c = __builtin_amdgcn_mfma_f32_16x16x32_bf16(qf0, kf0, c, 0, 0, 0);
            c = __builtin_amdgcn_mfma_f32_16x16x32_bf16(qf1, kf1, c, 0, 0, 0);
            #pragma unroll
            for (int r = 0; r < 4; ++r) s[nt][r] = c[r]*0.125f;
        }
        #pragma unroll
        for (int r = 0; r < 4; ++r) {
            int row = q0 + quad*4 + r;
            size_t wb = ((size_t)b*LL + row)*64 + kt*2;
            unsigned int w0 = mbits[wb], w1 = mbits[wb+1];
            #pragma unroll
            for (int nt = 0; nt < 4; ++nt) {
                unsigned int w = (nt < 2) ? w0 : w1;
                if (!((w >> (((nt&1)<<4) + l16)) & 1u)) s[nt][r] = -1e30f;
            }
        }
        #pragma unroll
        for (int r = 0; r < 4; ++r) {
            float rm = fmaxf(fmaxf(s[0][r], s[1][r]), fmaxf(s[2][r], s[3][r]));
            #pragma unroll
            for (int off = 1; off < 16; off <<= 1) rm = fmaxf(rm, __shfl_xor(rm, off));
            float mn = fmaxf(mrow[r], rm);
            float corr = __expf(mrow[r] - mn);
            float ps = __expf(s[0][r]-mn) + __expf(s[1][r]-mn) + __expf(s[2][r]-mn) + __expf(s[3][r]-mn);
            #pragma unroll
            for (int off = 1; off < 16; off <<= 1) ps += __shfl_xor(ps, off);
            lrow[r] = lrow[r]*corr + ps;
            mrow[r] = mn;
        }
    }
    float rinv[4];
    #pragma unroll
    for (int r = 0; r < 4; ++r) rinv[r] = 1.f / lrow[r];

    // ---- pass 2: recompute, write attn, accumulate O ----
    __shared__ unsigned short Pl[4][16][72];
    f32x4 oacc[4];
    #pragma unroll
    for (int i = 0; i < 4; ++i) oacc[i] = (f32x4){0.f,0.f,0.f,0.f};
    float* attn_b = attn + (size_t)bh * LL * LL;

    for (int kt = 0; kt < 32; ++kt) {
        #pragma unroll
        for (int nt = 0; nt < 4; ++nt) {
            const unsigned short* Kp = Kb + (size_t)(kt*64 + nt*16 + l16)*DKK;
            short8 kf0 = *(const short8*)(Kp + quad*8);
            short8 kf1 = *(const short8*)(Kp + 32 + quad*8);
            f32x4 c = (f32x4){0.f,0.f,0.f,0.f};
            c = __builtin_amdgcn_mfma_f32_16x16x32_bf16(qf0, kf0, c, 0, 0, 0);
            c = __builtin_amdgcn_mfma_f32_16x16x32_bf16(qf1, kf1, c, 0, 0, 0);
            #pragma unroll
            for (int r = 0; r < 4; ++r) {
                int row = q0 + quad*4 + r;
                float sv = c[r]*0.125f;
                size_t wb = ((size_t)b*LL + row)*64 + kt*2 + (nt>>1);
                unsigned int w = mbits[wb];
                int bit = (w >> (((nt&1)<<4) + l16)) & 1;
                float p = bit ? __expf(sv - mrow[r]) * rinv[r] : 0.f;
                attn_b[(size_t)row*LL + kt*64 + nt*16 + l16] = p;
                Pl[wv][quad*4 + r][nt*16 + l16] = f2bf(p);
            }
        }
        __syncthreads();
        #pragma unroll
        for (int c2 = 0; c2 < 2; ++c2) {
            short8 pf = *(const short8*)(&Pl[wv][l16][c2*32 + quad*8]);
            #pragma unroll
            for (int dt = 0; dt < 4; ++dt) {
                const unsigned short* Vp = Vb + (size_t)(dt*16 + l16)*LL + kt*64 + c2*32 + quad*8;
                short8 vf = *(const short8*)(Vp);
                oacc[dt] = __builtin_amdgcn_mfma_f32_16x16x32_bf16(pf, vf, oacc[dt], 0, 0, 0);
            }
        }
        __syncthreads();
    }
    #pragma unroll
    for (int dt = 0; dt < 4; ++dt) {
        #pragma unroll
        for (int r = 0; r < 4; ++r) {
            int row = q0 + quad*4 + r;
            size_t m = (size_t)b*LL + row;
            AO[m*DD + h*DKK + dt*16 + l16] = f2bf(oacc[dt][r]);
        }
    }
}

extern "C" void kernel_launch(void* const* d_in, const int* in_sizes, int n_in,
                              void* d_out, int out_size, void* d_ws, size_t ws_size,
                              hipStream_t stream) {
    const float* q  = (const float*)d_in[0];
    const float* k  = (const float*)d_in[1];
    const float* v  = (const float*)d_in[2];
    const int* mask = (const int*)d_in[3];
    const float* gq = (const float*)d_in[4];
    const float* bq = (const float*)d_in[5];
    const float* gk = (const float*)d_in[6];
    const float* bk = (const float*)d_in[7];
    const float* gv = (const float*)d_in[8];
    const float* bv = (const float*)d_in[9];
    const float* Wq = (const float*)d_in[10];
    const float* Wk = (const float*)d_in[11];
    const float* Wv = (const float*)d_in[12];
    const float* Wfc = (const float*)d_in[13];

    // workspace layout (ushort elements)
    unsigned short* Wb = (unsigned short*)d_ws;        // 4 x 1M bf16          (8 MB)
    unsigned short* xn = Wb + (size_t)4*DD*DD;         // 3 x 4.19M bf16       (24 MB)
    unsigned short* qh = xn + (size_t)3*BB*LL*DD;      // 4.19M bf16           (8 MB)
    unsigned short* kh = qh + (size_t)BB*LL*DD;        // 4.19M bf16           (8 MB)
    unsigned short* vT = kh + (size_t)BB*LL*DD;        // 4.19M bf16           (8 MB)
    unsigned int* mb  = (unsigned int*)(vT + (size_t)BB*LL*DD);  // 1.05 MB
    unsigned short* AO = xn;                           // alias: xn dead after projections

    float* out_main = (float*)d_out;                       // (B,L,D)
    float* out_attn = out_main + (size_t)BB*LL*DD;         // (B,H,L,L)

    dim3 blk(256);
    k_convw<<<dim3((DD*DD)/1024, 4), blk, 0, stream>>>(Wq, Wk, Wv, Wfc, Wb);
    k_mask<<<dim3((BB*LL*LL)/256), blk, 0, stream>>>(mask, (unsigned long long*)mb);
    k_ln<<<dim3(BB*LL, 3), blk, 0, stream>>>(q, k, v, gq, bq, gk, bk, gv, bv, xn);

    // projections: qh/kh row-major per head, vh transposed
    k_gemm<<<dim3(64, 16), blk, 0, stream>>>(xn,                         Wb,                       qh, nullptr, 0);
    k_gemm<<<dim3(64, 16), blk, 0, stream>>>(xn + (size_t)BB*LL*DD,      Wb + (size_t)DD*DD,       kh, nullptr, 0);
    k_gemm<<<dim3(64, 16), blk, 0, stream>>>(xn + (size_t)2*BB*LL*DD,    Wb + (size_t)2*DD*DD,     vT, nullptr, 1);

    k_attn<<<dim3(LL/64, BB*HH), blk, 0, stream>>>(qh, kh, vT, mb, out_attn, AO);

    // final projection + residual
    k_gemm<<<dim3(64, 16), blk, 0, stream>>>(AO, Wb + (size_t)3*DD*DD, out_main, q, 2);
}